// Round 3
// baseline (1393.993 us; speedup 1.0000x reference)
//
#include <hip/hip_runtime.h>
#include <math.h>

#define TT 1024
#define BB 8
#define DD 512
#define HH 8
#define HSZ 64
#define LL 6
#define FF4 2048

typedef __attribute__((ext_vector_type(8))) short short8;
typedef __attribute__((ext_vector_type(4))) float floatx4;
typedef unsigned short ushort_t;
typedef unsigned int uint_t;

__device__ __forceinline__ ushort_t f2bf(float f) {
  uint_t u = __float_as_uint(f);
  u += 0x7fff + ((u >> 16) & 1);  // RNE
  return (ushort_t)(u >> 16);
}
__device__ __forceinline__ float bf2f(ushort_t h) {
  return __uint_as_float(((uint_t)h) << 16);
}

// Packed MFMA-fragment layout for a [rows x Kd] bf16 matrix:
// tile (r16=row>>4, c32=col>>5); element index =
//   ((r16*(Kd>>5)+c32)<<9) + (((col>>3)&3)*16 + (row&15))*8 + (col&7)
// A wave's fragment (16 rows x 32 cols) is one contiguous 1KB chunk,
// lane i holding bytes [i*16, i*16+16) -> one coalesced global_load_dwordx4
// and one conflict-benign ds_write_b128/ds_read_b128.

// ---------------- embed + positional encoding ----------------
__global__ __launch_bounds__(256) void k_embed(const int* __restrict__ code,
                                               const float* __restrict__ emb,
                                               float* __restrict__ x,
                                               const int* __restrict__ lengths) {
  int idx = blockIdx.x * 256 + threadIdx.x;  // over B*T*D
  int c = idx & (DD - 1);
  int bt = idx >> 9;
  int t = bt & (TT - 1);
  if (t >= lengths[bt >> 10]) return;  // block-uniform (block spans half a row)
  int f = c >> 4, e = c & 15;
  int vv = code[bt * 32 + f];
  int i = c >> 1;
  float freq = expf((float)(2 * i) * (-9.210340371976184f / 512.f));
  float ang = (float)t * freq;
  float pe = (c & 1) ? cosf(ang) : sinf(ang);
  x[idx] = emb[vv * 16 + e] + pe;
}

// ---------------- layernorm: fp32 in -> packed bf16 (or linear fp32 + scores) ----------------
__global__ __launch_bounds__(256) void k_ln(const float* __restrict__ x,
                                            ushort_t* __restrict__ yB,
                                            float* __restrict__ yF,
                                            const float* __restrict__ g,
                                            const float* __restrict__ b,
                                            const float* __restrict__ aw,
                                            const float* __restrict__ ab,
                                            float* __restrict__ scores,
                                            const int* __restrict__ lengths) {
  int row0 = blockIdx.x * 4;
  if ((row0 & (TT - 1)) >= lengths[row0 >> 10]) return;  // 4 rows share a batch
  int wave = threadIdx.x >> 6, lane = threadIdx.x & 63;
  int row = row0 + wave;
  const float* xr = x + (size_t)row * DD;
  float v[8];
  *(float4*)&v[0] = *(const float4*)(xr + lane * 8);
  *(float4*)&v[4] = *(const float4*)(xr + lane * 8 + 4);
  float s = 0.f;
#pragma unroll
  for (int j = 0; j < 8; ++j) s += v[j];
#pragma unroll
  for (int off = 32; off; off >>= 1) s += __shfl_down(s, off, 64);
  float mean = __shfl(s, 0, 64) * (1.f / DD);
  float qv = 0.f;
#pragma unroll
  for (int j = 0; j < 8; ++j) { float d = v[j] - mean; qv += d * d; }
#pragma unroll
  for (int off = 32; off; off >>= 1) qv += __shfl_down(qv, off, 64);
  float rs = rsqrtf(__shfl(qv, 0, 64) * (1.f / DD) + 1e-5f);
  float ov[8];
  float sdot = 0.f;
#pragma unroll
  for (int e = 0; e < 8; ++e) {
    int c = lane * 8 + e;
    ov[e] = (v[e] - mean) * rs * g[c] + b[c];
    if (scores) sdot += ov[e] * aw[c];
  }
  if (yB) {
    short8 o8;
#pragma unroll
    for (int e = 0; e < 8; ++e) o8[e] = (short)f2bf(ov[e]);
    size_t ad = (((size_t)(row >> 4) * 16 + (lane >> 2)) << 9) + ((lane & 3) * 16 + (row & 15)) * 8;
    *(short8*)(yB + ad) = o8;
  } else {
    float* yr = yF + (size_t)row * DD + lane * 8;
    *(float4*)yr = *(float4*)&ov[0];
    *(float4*)(yr + 4) = *(float4*)&ov[4];
  }
  if (scores) {
#pragma unroll
    for (int off = 32; off; off >>= 1) sdot += __shfl_down(sdot, off, 64);
    if (lane == 0) scores[row] = sdot + ab[0];
  }
}

// ---------------- fp32 weights -> packed bf16 B-operand ----------------
__global__ __launch_bounds__(256) void k_packw(const float* __restrict__ in,
                                               ushort_t* __restrict__ out,
                                               int Nin, long in_ms, int nh,
                                               long os_l, int nblk, int Kout) {
  __shared__ float t4[64][65];
  int mz = blockIdx.z;
  const float* ip = in + (size_t)mz * in_ms;
  ushort_t* op = out + (size_t)(mz / nh) * os_l;
  int nbase = (mz % nh) * nblk + blockIdx.y * 64;
  int k0 = blockIdx.x * 64;
  int cc = threadIdx.x & 63, r0 = threadIdx.x >> 6;
#pragma unroll
  for (int i = 0; i < 16; ++i) {
    int r = r0 * 16 + i;
    t4[r][cc] = ip[(size_t)(k0 + r) * Nin + (nbase - (mz % nh) * nblk) + cc];
  }
  __syncthreads();
#pragma unroll
  for (int half = 0; half < 2; ++half) {
    int c = threadIdx.x + half * 256;
    int joct = c >> 6, nl = c & 63;
    int n = nbase + nl, k = k0 + joct * 8;
    short8 v8;
#pragma unroll
    for (int e = 0; e < 8; ++e) v8[e] = (short)f2bf(t4[joct * 8 + e][nl]);
    size_t ad = (((size_t)(n >> 4) * (Kout >> 5) + (k >> 5)) << 9) + (((k >> 3) & 3) * 16 + (n & 15)) * 8;
    *(short8*)(op + ad) = v8;
  }
}

// ---------------- staged MFMA GEMM: 4 waves, LDS double-buffer (m97 structure) ----------------
// R2 post-mortem: 1-wave tiles have zero operand reuse -> ~790 MB L2 stream per
// GEMM (~17 TB/s, latency-coupled) and MfmaUtil ~9% regardless of occupancy/ring
// depth. Fix: block tile staged once into LDS, 4 waves consume (reuse 4-8x).
// BN=128: 128x128 tile, waves in 2x2 quadrants of 64x64 (MT=NT=4).
// BN=64:  128x64 tile, waves in 4 row-bands of 32x64 (MT=2, NT=4).
// BK=32 (one fragment column). Stage: each wave loads NFRAG/4 fragments
// (global 16B/lane -> VGPR -> ds_write_b128), double-buffered, one
// __syncthreads() per k-step; next-k global loads issued before the MFMA block.
// mode 0: outB linear bf16; mode 3: same + q-part (col<512) scaled by 0.125;
// mode 1: outF = acc+bias+resid (fp32); mode 2 (BN=128): outB packed bf16 gelu.
// lengths: 128-row M-tiles fully past len[batch] are dead -> skip block.
template <int BN>
__global__ __launch_bounds__(256, 3) void k_sgemm(const ushort_t* __restrict__ Apk,
                                                  const ushort_t* __restrict__ Bpk,
                                                  const float* __restrict__ resid,
                                                  const float* __restrict__ bias,
                                                  float* __restrict__ outF,
                                                  ushort_t* __restrict__ outB,
                                                  int M, int N, int K, int mode,
                                                  const int* __restrict__ lengths) {
  constexpr int MT = (BN == 128) ? 4 : 2;
  constexpr int NT = 4;
  constexpr int NA = 8;            // A fragments per k-step (BM=128)
  constexpr int NB = BN / 16;      // B fragments per k-step
  constexpr int NFRAG = NA + NB;   // 16 or 12
  constexpr int NF = NFRAG / 4;    // fragments staged per wave (4 or 3)
  constexpr int BUFU = NFRAG * 512;  // ushort units per buffer (1KB/frag)
  // BN=128: epilogue mode-2 shuffle needs 4 waves x 10KB = 40KB >= 2x16KB buffers.
  __shared__ ushort_t lds[(BN == 128) ? 20480 : 2 * BUFU];

  const int tid = threadIdx.x;
  const int w = tid >> 6, lane = tid & 63;
  const int quad = lane >> 4, l16 = lane & 15;
  const int gx = N / BN;
  int id = blockIdx.x;
  int bx = (id >> 3) % gx;
  int by = (id / (8 * gx)) * 8 + (id & 7);  // same-row tiles share an XCD
  const int row0 = by * 128, col0 = bx * BN;
  if (lengths && (row0 & (TT - 1)) >= lengths[row0 >> 10]) return;
  const int nk = K >> 5;

  // wave's quadrant/band within the block tile
  const int wrow0 = (BN == 128) ? row0 + (w >> 1) * 64 : row0 + w * 32;
  const int wcol0 = (BN == 128) ? col0 + (w & 1) * 64 : col0;
  const int ar16 = (wrow0 - row0) >> 4;          // first A slot for this wave
  const int bc16 = NA + ((wcol0 - col0) >> 4);   // first B slot for this wave

  // per-wave stage source pointers (fragment base + lane offset), k term added per step
  const ushort_t* gbase[NF];
#pragma unroll
  for (int i = 0; i < NF; ++i) {
    int f = w * NF + i;
    if (f < NA)
      gbase[i] = Apk + (((size_t)((row0 >> 4) + f) * nk) << 9) + lane * 8;
    else
      gbase[i] = Bpk + (((size_t)((col0 >> 4) + (f - NA)) * nk) << 9) + lane * 8;
  }
  const int ldst = (w * NF) * 512 + lane * 8;  // wave's stage dest within a buffer

  floatx4 acc[MT][NT] = {};
  short8 greg[NF];

  // prologue: stage k-step 0 into buffer 0
#pragma unroll
  for (int i = 0; i < NF; ++i) greg[i] = *(const short8*)(gbase[i]);
#pragma unroll
  for (int i = 0; i < NF; ++i) *(short8*)&lds[ldst + i * 512] = greg[i];
  __syncthreads();

  int bufo = 0;
  for (int kc = 0; kc + 1 < nk; ++kc) {
    // issue next-k global loads first (latency hides under ds_read+MFMA)
#pragma unroll
    for (int i = 0; i < NF; ++i)
      greg[i] = *(const short8*)(gbase[i] + ((size_t)(kc + 1) << 9));
    short8 af[MT], bfv[NT];
#pragma unroll
    for (int mt = 0; mt < MT; ++mt) af[mt] = *(const short8*)&lds[bufo + (ar16 + mt) * 512 + lane * 8];
#pragma unroll
    for (int nt = 0; nt < NT; ++nt) bfv[nt] = *(const short8*)&lds[bufo + (bc16 + nt) * 512 + lane * 8];
#pragma unroll
    for (int mt = 0; mt < MT; ++mt)
#pragma unroll
      for (int nt = 0; nt < NT; ++nt)
        acc[mt][nt] = __builtin_amdgcn_mfma_f32_16x16x32_bf16(af[mt], bfv[nt], acc[mt][nt], 0, 0, 0);
    const int nbufo = bufo ^ BUFU;
#pragma unroll
    for (int i = 0; i < NF; ++i) *(short8*)&lds[nbufo + ldst + i * 512] = greg[i];
    __syncthreads();
    bufo = nbufo;
  }
  // tail k-step (no stage)
  {
    short8 af[MT], bfv[NT];
#pragma unroll
    for (int mt = 0; mt < MT; ++mt) af[mt] = *(const short8*)&lds[bufo + (ar16 + mt) * 512 + lane * 8];
#pragma unroll
    for (int nt = 0; nt < NT; ++nt) bfv[nt] = *(const short8*)&lds[bufo + (bc16 + nt) * 512 + lane * 8];
#pragma unroll
    for (int mt = 0; mt < MT; ++mt)
#pragma unroll
      for (int nt = 0; nt < NT; ++nt)
        acc[mt][nt] = __builtin_amdgcn_mfma_f32_16x16x32_bf16(af[mt], bfv[nt], acc[mt][nt], 0, 0, 0);
  }

  if (BN == 128 && mode == 2) {
    // gelu(acc+bias) -> per-wave LDS shuffle -> packed bf16 (Kd = N)
    __syncthreads();  // staging buffers are being reused as shuffle space
    ushort_t* Cb = &lds[w * 5120];
#pragma unroll
    for (int mt = 0; mt < MT; ++mt)
#pragma unroll
      for (int nt = 0; nt < NT; ++nt) {
        floatx4 a4 = acc[mt][nt];
#pragma unroll
        for (int r = 0; r < 4; ++r) {
          float val = a4[r] + bias[wcol0 + nt * 16 + l16];
          val = 0.5f * val * (1.f + erff(val * 0.7071067811865475f));
          Cb[(mt * 16 + quad * 4 + r) * 80 + nt * 16 + l16] = f2bf(val);
        }
      }
#pragma unroll
    for (int mt2 = 0; mt2 < 4; ++mt2)
#pragma unroll
      for (int kt2 = 0; kt2 < 2; ++kt2) {
        short8 v8 = *(const short8*)&Cb[(mt2 * 16 + l16) * 80 + kt2 * 32 + quad * 8];
        size_t ad = ((((size_t)(wrow0 >> 4) + mt2) * (N >> 5) + (wcol0 >> 5) + kt2) << 9) + lane * 8;
        *(short8*)(outB + ad) = v8;
      }
  } else {
    const float qscale = (mode == 3 && col0 < 512) ? 0.125f : 1.0f;  // pre-scale Q for attn
#pragma unroll
    for (int mt = 0; mt < MT; ++mt)
#pragma unroll
      for (int nt = 0; nt < NT; ++nt) {
        floatx4 a4 = acc[mt][nt];
#pragma unroll
        for (int r = 0; r < 4; ++r) {
          int row = wrow0 + mt * 16 + quad * 4 + r;
          int col = wcol0 + nt * 16 + l16;
          float val = a4[r];
          if (bias) val += bias[col];
          size_t idx = (size_t)row * N + col;
          if (mode == 1) outF[idx] = val + resid[idx];
          else outB[idx] = f2bf(val * qscale);
        }
      }
  }
}

// ---------------- MFMA flash attention, fixed-max softmax ----------------
__global__ __launch_bounds__(256) void k_attn(const ushort_t* __restrict__ qkv,
                                              const int* __restrict__ lengths,
                                              ushort_t* __restrict__ o) {
  __shared__ ushort_t Ks[64 * 72];
  __shared__ ushort_t Vt[64 * 72];
  __shared__ ushort_t Ps[4][16 * 72];  // stride 72: 2-way banks only (m136-free)
  const int tid = threadIdx.x;
  const int w = tid >> 6, lane = tid & 63;
  const int quad = lane >> 4, l16 = lane & 15;
  const int tile = blockIdx.x & 15;
  const int bh = blockIdx.x >> 4;
  const int b = bh >> 3, h = bh & 7;
  const int len = lengths[b];
  if (tile * 64 >= len) return;  // block-uniform: all waves exit together
  const int tqa = tile * 64 + w * 16 + l16;
  const ushort_t* qp = qkv + ((size_t)(b * TT + tqa)) * 1536 + h * HSZ + quad * 8;
  short8 qf0 = *(const short8*)qp;
  short8 qf1 = *(const short8*)(qp + 32);
  floatx4 oacc[4] = {};
  float lsum[4] = {0.f, 0.f, 0.f, 0.f};
  const int skey = tid >> 2, sseg = (tid & 3) << 4;
  const int vkp = (tid & 31) << 1, vds = (tid >> 5) << 3;
  const int nkt = (len + 63) >> 6;
  for (int kt = 0; kt < nkt; ++kt) {
    const int s0 = kt * 64;
    __syncthreads();
    {
      const ushort_t* kp = qkv + ((size_t)(b * TT + s0 + skey)) * 1536 + 512 + h * HSZ + sseg;
      short8 k0 = *(const short8*)kp;
      short8 k1 = *(const short8*)(kp + 8);
      *(short8*)&Ks[skey * 72 + sseg] = k0;
      *(short8*)&Ks[skey * 72 + sseg + 8] = k1;
      const ushort_t* vp0 = qkv + ((size_t)(b * TT + s0 + vkp)) * 1536 + 1024 + h * HSZ + vds;
      short8 v0 = *(const short8*)vp0;
      short8 v1 = *(const short8*)(vp0 + 1536);
#pragma unroll
      for (int i = 0; i < 8; ++i) {
        ushort2 pr;
        pr.x = (ushort_t)v0[i];
        pr.y = (ushort_t)v1[i];
        *(ushort2*)&Vt[(vds + i) * 72 + vkp] = pr;
      }
    }
    __syncthreads();
    floatx4 sacc[4] = {};
#pragma unroll
    for (int nt = 0; nt < 4; ++nt) {
      short8 kf0 = *(const short8*)&Ks[(nt * 16 + l16) * 72 + quad * 8];
      short8 kf1 = *(const short8*)&Ks[(nt * 16 + l16) * 72 + 32 + quad * 8];
      sacc[nt] = __builtin_amdgcn_mfma_f32_16x16x32_bf16(qf0, kf0, sacc[nt], 0, 0, 0);
      sacc[nt] = __builtin_amdgcn_mfma_f32_16x16x32_bf16(qf1, kf1, sacc[nt], 0, 0, 0);
    }
    // p = exp(score); mask only the tail tile (wave-uniform branch)
    float p[4][4];
    if (kt == nkt - 1) {
#pragma unroll
      for (int nt = 0; nt < 4; ++nt) {
        bool valid = (s0 + nt * 16 + l16 < len);
#pragma unroll
        for (int r = 0; r < 4; ++r) p[nt][r] = valid ? __expf(sacc[nt][r]) : 0.f;
      }
    } else {
#pragma unroll
      for (int nt = 0; nt < 4; ++nt)
#pragma unroll
        for (int r = 0; r < 4; ++r) p[nt][r] = __expf(sacc[nt][r]);
    }
#pragma unroll
    for (int r = 0; r < 4; ++r)
#pragma unroll
      for (int nt = 0; nt < 4; ++nt) {
        lsum[r] += p[nt][r];
        Ps[w][(quad * 4 + r) * 72 + nt * 16 + l16] = f2bf(p[nt][r]);
      }
    short8 pf0 = *(const short8*)&Ps[w][l16 * 72 + quad * 8];
    short8 pf1 = *(const short8*)&Ps[w][l16 * 72 + 32 + quad * 8];
#pragma unroll
    for (int nt = 0; nt < 4; ++nt) {
      short8 vf0 = *(const short8*)&Vt[(nt * 16 + l16) * 72 + quad * 8];
      short8 vf1 = *(const short8*)&Vt[(nt * 16 + l16) * 72 + 32 + quad * 8];
      oacc[nt] = __builtin_amdgcn_mfma_f32_16x16x32_bf16(pf0, vf0, oacc[nt], 0, 0, 0);
      oacc[nt] = __builtin_amdgcn_mfma_f32_16x16x32_bf16(pf1, vf1, oacc[nt], 0, 0, 0);
    }
  }
  // one deferred row-sum reduction across the 16 key-lanes
#pragma unroll
  for (int off = 1; off < 16; off <<= 1) {
#pragma unroll
    for (int r = 0; r < 4; ++r) lsum[r] += __shfl_xor(lsum[r], off, 64);
  }
  // epilogue: per-wave LDS shuffle into packed-A layout (Kd=512)
#pragma unroll
  for (int r = 0; r < 4; ++r) {
    int t = tile * 64 + w * 16 + quad * 4 + r;
    float inv = (t < len) ? 1.f / lsum[r] : 0.f;  // row mask
#pragma unroll
    for (int nt = 0; nt < 4; ++nt)
      Ps[w][(quad * 4 + r) * 72 + nt * 16 + l16] = f2bf(oacc[nt][r] * inv);
  }
  const int mtile = b * 64 + tile * 4 + w;
#pragma unroll
  for (int kt2 = 0; kt2 < 2; ++kt2) {
    short8 v8 = *(const short8*)&Ps[w][l16 * 72 + kt2 * 32 + quad * 8];
    size_t ad = (((size_t)mtile * 16 + h * 2 + kt2) << 9) + lane * 8;
    *(short8*)(o + ad) = v8;
  }
}

// ---------------- pool softmax: scores -> weights (per batch) ----------------
__global__ __launch_bounds__(256) void k_softw(const float* __restrict__ scores,
                                               const int* __restrict__ lengths,
                                               float* __restrict__ wts) {
  __shared__ float red[8];
  int tid = threadIdx.x, b = blockIdx.x;
  int len = lengths[b];
  const float* sb = scores + b * TT;
  float m = -1e30f;
  for (int t = tid; t < len; t += 256) m = fmaxf(m, sb[t]);
#pragma unroll
  for (int off = 32; off; off >>= 1) m = fmaxf(m, __shfl_down(m, off, 64));
  if ((tid & 63) == 0) red[tid >> 6] = m;
  __syncthreads();
  m = fmaxf(fmaxf(red[0], red[1]), fmaxf(red[2], red[3]));
  float ssum = 0.f;
  for (int t = tid; t < len; t += 256) ssum += __expf(sb[t] - m);
#pragma unroll
  for (int off = 32; off; off >>= 1) ssum += __shfl_down(ssum, off, 64);
  if ((tid & 63) == 0) red[4 + (tid >> 6)] = ssum;
  __syncthreads();
  float inv = 1.f / (red[4] + red[5] + red[6] + red[7]);
  for (int t = tid; t < TT; t += 256)
    wts[b * TT + t] = (t < len) ? __expf(sb[t] - m) * inv : 0.f;
}

// ---------------- weighted sum partials: grid (B, 16), 64 rows each ----------------
__global__ __launch_bounds__(256) void k_wsum(const float* __restrict__ xf,
                                              const float* __restrict__ wts,
                                              float* __restrict__ partial,
                                              const int* __restrict__ lengths) {
  int b = blockIdx.x, c = blockIdx.y, tid = threadIdx.x;
  float* pp = partial + ((size_t)b * 16 + c) * DD;
  if (c * 64 >= lengths[b]) {  // dead chunk: weights all zero
    pp[tid] = 0.f;
    pp[tid + 256] = 0.f;
    return;
  }
  const float* xb = xf + ((size_t)b * TT + c * 64) * DD;
  const float* wb = wts + b * TT + c * 64;
  float a0 = 0.f, a1 = 0.f;
  for (int t = 0; t < 64; ++t) {
    float wv = wb[t];
    a0 += wv * xb[(size_t)t * DD + tid];
    a1 += wv * xb[(size_t)t * DD + tid + 256];
  }
  pp[tid] = a0;
  pp[tid + 256] = a1;
}

// ---------------- classification head (reduces the 16 partials) ----------------
__global__ __launch_bounds__(64) void k_head(const float* __restrict__ partial,
                                             const float* __restrict__ head_w,
                                             const float* __restrict__ head_b,
                                             float* __restrict__ out) {
  __shared__ float ssum[DD];
  int b = blockIdx.x, tid = threadIdx.x;
  for (int d = tid; d < DD; d += 64) {
    float s = 0.f;
#pragma unroll
    for (int c = 0; c < 16; ++c) s += partial[((size_t)b * 16 + c) * DD + d];
    ssum[d] = s;
  }
  __syncthreads();
  if (tid < 49) {
    float s = head_b[tid];
    for (int d = 0; d < DD; ++d) s += ssum[d] * head_w[d * 49 + tid];
    out[b * 49 + tid] = s;
  }
}

extern "C" void kernel_launch(void* const* d_in, const int* in_sizes, int n_in,
                              void* d_out, int out_size, void* d_ws, size_t ws_size,
                              hipStream_t stream) {
  const int* code = (const int*)d_in[0];
  const int* lengths = (const int*)d_in[1];
  const float* emb = (const float*)d_in[2];
  const float* Wq = (const float*)d_in[3];
  const float* Wk = (const float*)d_in[4];
  const float* Wv = (const float*)d_in[5];
  const float* Wo = (const float*)d_in[6];
  const float* bo = (const float*)d_in[7];
  const float* W1 = (const float*)d_in[8];
  const float* b1 = (const float*)d_in[9];
  const float* W2 = (const float*)d_in[10];
  const float* b2 = (const float*)d_in[11];
  const float* ln1_g = (const float*)d_in[12];
  const float* ln1_b = (const float*)d_in[13];
  const float* ln2_g = (const float*)d_in[14];
  const float* ln2_b = (const float*)d_in[15];
  const float* lnf_g = (const float*)d_in[16];
  const float* lnf_b = (const float*)d_in[17];
  const float* attn_w = (const float*)d_in[18];
  const float* attn_b = (const float*)d_in[19];
  const float* head_w = (const float*)d_in[20];
  const float* head_b = (const float*)d_in[21];
  float* out = (float*)d_out;

  const size_t NTOK = (size_t)BB * TT;  // 8192
  float* x = (float*)d_ws;                       // 8192*512 fp32
  ushort_t* xn = (ushort_t*)(x + NTOK * DD);     // 8192*512 bf16 (packed)
  ushort_t* un = xn + NTOK * DD;                 // union: qkv | h1 | xf
  ushort_t* qkv = un;                            // linear bf16
  ushort_t* h1 = un;                             // packed bf16
  float* xf = (float*)un;
  ushort_t* wqpk = un + (size_t)NTOK * FF4;      // packed 6x 1536x512
  ushort_t* wopk = wqpk + (size_t)LL * 1536 * 512;
  ushort_t* w1pk = wopk + (size_t)LL * 512 * 512;
  ushort_t* w2pk = w1pk + (size_t)LL * 512 * FF4;
  float* scores = (float*)(w2pk + (size_t)LL * FF4 * 512);  // 8192
  float* wts = scores + NTOK;                               // 8192
  float* partial = wts + NTOK;                              // 8*16*512

  // weight packing (fp32 [k][n] -> packed bf16 fragments)
  k_packw<<<dim3(8, 1, 48), 256, 0, stream>>>(Wq, wqpk,              64, (long)512 * 64, 8, (long)1536 * 512, 64, 512);
  k_packw<<<dim3(8, 1, 48), 256, 0, stream>>>(Wk, wqpk + 512 * 512,  64, (long)512 * 64, 8, (long)1536 * 512, 64, 512);
  k_packw<<<dim3(8, 1, 48), 256, 0, stream>>>(Wv, wqpk + 1024 * 512, 64, (long)512 * 64, 8, (long)1536 * 512, 64, 512);
  k_packw<<<dim3(8, 8, 6), 256, 0, stream>>>(Wo, wopk, 512, (long)512 * 512, 1, (long)512 * 512, 0, 512);
  k_packw<<<dim3(8, 32, 6), 256, 0, stream>>>(W1, w1pk, 2048, (long)512 * 2048, 1, (long)2048 * 512, 0, 512);
  k_packw<<<dim3(32, 8, 6), 256, 0, stream>>>(W2, w2pk, 512, (long)2048 * 512, 1, (long)512 * 2048, 0, 2048);

  k_embed<<<dim3((unsigned)((NTOK * DD) / 256)), dim3(256), 0, stream>>>(code, emb, x, lengths);

  for (int l = 0; l < LL; ++l) {
    k_ln<<<dim3(NTOK / 4), 256, 0, stream>>>(x, xn, nullptr, ln1_g + l * DD, ln1_b + l * DD,
                                             nullptr, nullptr, nullptr, lengths);
    // QKV (mode 3): 128x128 tiles -> 64x12 = 768 blocks of 4 waves
    k_sgemm<128><<<dim3(768), 256, 0, stream>>>(xn, wqpk + (size_t)l * 1536 * 512, nullptr, nullptr,
                                                nullptr, qkv, (int)NTOK, 1536, 512, 3, lengths);
    k_attn<<<dim3(BB * HH * (TT / 64)), 256, 0, stream>>>(qkv, lengths, xn);
    // Wo + bias + residual -> x (fp32): 128x64 tiles -> 512 blocks
    k_sgemm<64><<<dim3(512), 256, 0, stream>>>(xn, wopk + (size_t)l * 512 * 512, x, bo + l * DD,
                                               x, nullptr, (int)NTOK, 512, 512, 1, lengths);
    k_ln<<<dim3(NTOK / 4), 256, 0, stream>>>(x, xn, nullptr, ln2_g + l * DD, ln2_b + l * DD,
                                             nullptr, nullptr, nullptr, lengths);
    // W1 + bias + GELU -> h1 (packed bf16): 128x128 tiles -> 64x16 = 1024 blocks
    k_sgemm<128><<<dim3(1024), 256, 0, stream>>>(xn, w1pk + (size_t)l * 512 * FF4, nullptr, b1 + l * FF4,
                                                 nullptr, h1, (int)NTOK, FF4, 512, 2, lengths);
    // W2 + bias + residual -> x (fp32): K=2048, 128x64 tiles -> 512 blocks
    k_sgemm<64><<<dim3(512), 256, 0, stream>>>(h1, w2pk + (size_t)l * FF4 * 512, x, b2 + l * DD,
                                               x, nullptr, (int)NTOK, 512, 2048, 1, lengths);
  }
  k_ln<<<dim3(NTOK / 4), 256, 0, stream>>>(x, nullptr, xf, lnf_g, lnf_b,
                                           attn_w, attn_b, scores, lengths);
  k_softw<<<dim3(BB), 256, 0, stream>>>(scores, lengths, wts);
  k_wsum<<<dim3(BB, 16), 256, 0, stream>>>(xf, wts, partial, lengths);
  k_head<<<dim3(BB), 64, 0, stream>>>(partial, head_w, head_b, out);
}

// Round 4
// 1236.123 us; speedup vs baseline: 1.1277x; 1.1277x over previous
//
#include <hip/hip_runtime.h>
#include <math.h>

#define TT 1024
#define BB 8
#define DD 512
#define HH 8
#define HSZ 64
#define LL 6
#define FF4 2048

typedef __attribute__((ext_vector_type(8))) short short8;
typedef __attribute__((ext_vector_type(4))) float floatx4;
typedef unsigned short ushort_t;
typedef unsigned int uint_t;

__device__ __forceinline__ ushort_t f2bf(float f) {
  uint_t u = __float_as_uint(f);
  u += 0x7fff + ((u >> 16) & 1);  // RNE
  return (ushort_t)(u >> 16);
}
__device__ __forceinline__ float bf2f(ushort_t h) {
  return __uint_as_float(((uint_t)h) << 16);
}

// async global->LDS DMA, 16B/lane. LDS dest is wave-uniform base + lane*16;
// global src is per-lane. Our packed-fragment layout is exactly this pattern.
typedef const __attribute__((address_space(1))) uint_t* gas_t;
typedef __attribute__((address_space(3))) uint_t* las_t;
__device__ __forceinline__ void stage16(const ushort_t* g, ushort_t* l) {
  __builtin_amdgcn_global_load_lds((gas_t)g, (las_t)l, 16, 0, 0);
}

// Packed MFMA-fragment layout for a [rows x Kd] bf16 matrix:
// tile (r16=row>>4, c32=col>>5); element index =
//   ((r16*(Kd>>5)+c32)<<9) + (((col>>3)&3)*16 + (row&15))*8 + (col&7)
// A wave's fragment (16 rows x 32 cols) is one contiguous 1KB chunk,
// lane i holding bytes [i*16, i*16+16) -> one coalesced global_load_lds_dwordx4
// and one conflict-benign ds_read_b128.

// ---------------- embed + positional encoding ----------------
__global__ __launch_bounds__(256) void k_embed(const int* __restrict__ code,
                                               const float* __restrict__ emb,
                                               float* __restrict__ x,
                                               const int* __restrict__ lengths) {
  int idx = blockIdx.x * 256 + threadIdx.x;  // over B*T*D
  int c = idx & (DD - 1);
  int bt = idx >> 9;
  int t = bt & (TT - 1);
  if (t >= lengths[bt >> 10]) return;  // block-uniform (block spans half a row)
  int f = c >> 4, e = c & 15;
  int vv = code[bt * 32 + f];
  int i = c >> 1;
  float freq = expf((float)(2 * i) * (-9.210340371976184f / 512.f));
  float ang = (float)t * freq;
  float pe = (c & 1) ? cosf(ang) : sinf(ang);
  x[idx] = emb[vv * 16 + e] + pe;
}

// ---------------- layernorm: fp32 in -> packed bf16 (or linear fp32 + scores) ----------------
__global__ __launch_bounds__(256) void k_ln(const float* __restrict__ x,
                                            ushort_t* __restrict__ yB,
                                            float* __restrict__ yF,
                                            const float* __restrict__ g,
                                            const float* __restrict__ b,
                                            const float* __restrict__ aw,
                                            const float* __restrict__ ab,
                                            float* __restrict__ scores,
                                            const int* __restrict__ lengths) {
  int row0 = blockIdx.x * 4;
  if ((row0 & (TT - 1)) >= lengths[row0 >> 10]) return;  // 4 rows share a batch
  int wave = threadIdx.x >> 6, lane = threadIdx.x & 63;
  int row = row0 + wave;
  const float* xr = x + (size_t)row * DD;
  float v[8];
  *(float4*)&v[0] = *(const float4*)(xr + lane * 8);
  *(float4*)&v[4] = *(const float4*)(xr + lane * 8 + 4);
  float s = 0.f;
#pragma unroll
  for (int j = 0; j < 8; ++j) s += v[j];
#pragma unroll
  for (int off = 32; off; off >>= 1) s += __shfl_down(s, off, 64);
  float mean = __shfl(s, 0, 64) * (1.f / DD);
  float qv = 0.f;
#pragma unroll
  for (int j = 0; j < 8; ++j) { float d = v[j] - mean; qv += d * d; }
#pragma unroll
  for (int off = 32; off; off >>= 1) qv += __shfl_down(qv, off, 64);
  float rs = rsqrtf(__shfl(qv, 0, 64) * (1.f / DD) + 1e-5f);
  float ov[8];
  float sdot = 0.f;
#pragma unroll
  for (int e = 0; e < 8; ++e) {
    int c = lane * 8 + e;
    ov[e] = (v[e] - mean) * rs * g[c] + b[c];
    if (scores) sdot += ov[e] * aw[c];
  }
  if (yB) {
    short8 o8;
#pragma unroll
    for (int e = 0; e < 8; ++e) o8[e] = (short)f2bf(ov[e]);
    size_t ad = (((size_t)(row >> 4) * 16 + (lane >> 2)) << 9) + ((lane & 3) * 16 + (row & 15)) * 8;
    *(short8*)(yB + ad) = o8;
  } else {
    float* yr = yF + (size_t)row * DD + lane * 8;
    *(float4*)yr = *(float4*)&ov[0];
    *(float4*)(yr + 4) = *(float4*)&ov[4];
  }
  if (scores) {
#pragma unroll
    for (int off = 32; off; off >>= 1) sdot += __shfl_down(sdot, off, 64);
    if (lane == 0) scores[row] = sdot + ab[0];
  }
}

// ---------------- fp32 weights -> packed bf16 B-operand ----------------
__global__ __launch_bounds__(256) void k_packw(const float* __restrict__ in,
                                               ushort_t* __restrict__ out,
                                               int Nin, long in_ms, int nh,
                                               long os_l, int nblk, int Kout) {
  __shared__ float t4[64][65];
  int mz = blockIdx.z;
  const float* ip = in + (size_t)mz * in_ms;
  ushort_t* op = out + (size_t)(mz / nh) * os_l;
  int nbase = (mz % nh) * nblk + blockIdx.y * 64;
  int k0 = blockIdx.x * 64;
  int cc = threadIdx.x & 63, r0 = threadIdx.x >> 6;
#pragma unroll
  for (int i = 0; i < 16; ++i) {
    int r = r0 * 16 + i;
    t4[r][cc] = ip[(size_t)(k0 + r) * Nin + (nbase - (mz % nh) * nblk) + cc];
  }
  __syncthreads();
#pragma unroll
  for (int half = 0; half < 2; ++half) {
    int c = threadIdx.x + half * 256;
    int joct = c >> 6, nl = c & 63;
    int n = nbase + nl, k = k0 + joct * 8;
    short8 v8;
#pragma unroll
    for (int e = 0; e < 8; ++e) v8[e] = (short)f2bf(t4[joct * 8 + e][nl]);
    size_t ad = (((size_t)(n >> 4) * (Kout >> 5) + (k >> 5)) << 9) + (((k >> 3) & 3) * 16 + (n & 15)) * 8;
    *(short8*)(op + ad) = v8;
  }
}

// ---------------- staged MFMA GEMM: 4 waves, global_load_lds double-buffer ----------------
// R3 post-mortem: reg-staged LDS GEMM = same ~9% MfmaUtil as 1-wave variants ->
// latency exposed by the per-k-step load->vmcnt->ds_write->barrier chain, plus
// grid starvation for the N=512 GEMMs (1.5 blocks/CU). Fixes (m97/m151):
// (a) global_load_lds width-16 async staging: issue next-k DMA early, no VGPR
//     round-trip, single drain at the barrier;
// (b) BM=BN=64 for Wo/W2 -> 1024 blocks (~3 live blocks/CU).
// Waves in 2x2 quadrants of (BM/2)x(BN/2). BK=32 (one fragment column).
// mode 0: outB linear bf16; mode 3: same + q-part (col<512) scaled by 0.125;
// mode 1: outF = acc+bias+resid (fp32); mode 2 (BM=128): outB packed bf16 gelu.
// lengths: M-tiles fully past len[batch] are dead -> skip block.
template <int BM, int BN>
__global__ __launch_bounds__(256, (BM == 128) ? 3 : 4) void k_agemm(const ushort_t* __restrict__ Apk,
                                                                    const ushort_t* __restrict__ Bpk,
                                                                    const float* __restrict__ resid,
                                                                    const float* __restrict__ bias,
                                                                    float* __restrict__ outF,
                                                                    ushort_t* __restrict__ outB,
                                                                    int M, int N, int K, int mode,
                                                                    const int* __restrict__ lengths) {
  constexpr int MT = BM / 32;      // MFMA row-frags per wave
  constexpr int NT = BN / 32;      // MFMA col-frags per wave
  constexpr int NA = BM / 16;      // A fragments per k-step
  constexpr int NB = BN / 16;      // B fragments per k-step
  constexpr int NFRAG = NA + NB;
  constexpr int NF = NFRAG / 4;    // fragments staged per wave
  constexpr int BUFU = NFRAG * 512;  // ushort units per buffer (1KB/frag)
  // BM=128: mode-2 epilogue shuffle needs 4 waves x 10KB = 40KB >= 2x16KB dbuf.
  __shared__ ushort_t lds[(BM == 128) ? 20480 : 2 * NFRAG * 512];

  const int tid = threadIdx.x;
  const int w = tid >> 6, lane = tid & 63;
  const int quad = lane >> 4, l16 = lane & 15;
  const int gx = N / BN;
  int id = blockIdx.x;
  int bx = (id >> 3) % gx;
  int by = (id / (8 * gx)) * 8 + (id & 7);  // same-row tiles share an XCD
  const int row0 = by * BM, col0 = bx * BN;
  if (lengths && (row0 & (TT - 1)) >= lengths[row0 >> 10]) return;
  const int nk = K >> 5;

  // wave's quadrant within the block tile
  const int wrow0 = row0 + (w >> 1) * (BM / 2);
  const int wcol0 = col0 + (w & 1) * (BN / 2);
  const int ar16 = (w >> 1) * MT;        // first A slot for this wave
  const int bc16 = NA + (w & 1) * NT;    // first B slot for this wave

  // per-wave stage sources (fragment base + lane*16B) and LDS slot offsets
  const ushort_t* gsrc[NF];
  int slot[NF];
#pragma unroll
  for (int i = 0; i < NF; ++i) {
    int f = w * NF + i;
    if (f < NA)
      gsrc[i] = Apk + (((size_t)((row0 >> 4) + f) * nk) << 9) + lane * 8;
    else
      gsrc[i] = Bpk + (((size_t)((col0 >> 4) + (f - NA)) * nk) << 9) + lane * 8;
    slot[i] = f * 512;
  }

  floatx4 acc[MT][NT] = {};

  // prologue: async-stage k-step 0 into buffer 0
#pragma unroll
  for (int i = 0; i < NF; ++i) stage16(gsrc[i], &lds[slot[i]]);
  __syncthreads();

  int bufo = 0;
  for (int kc = 0; kc + 1 < nk; ++kc) {
    const int nbufo = bufo ^ BUFU;
    // issue next-k DMA first; it drains at the barrier below
#pragma unroll
    for (int i = 0; i < NF; ++i)
      stage16(gsrc[i] + ((size_t)(kc + 1) << 9), &lds[nbufo + slot[i]]);
    short8 af[MT], bfv[NT];
#pragma unroll
    for (int mt = 0; mt < MT; ++mt) af[mt] = *(const short8*)&lds[bufo + (ar16 + mt) * 512 + lane * 8];
#pragma unroll
    for (int nt = 0; nt < NT; ++nt) bfv[nt] = *(const short8*)&lds[bufo + (bc16 + nt) * 512 + lane * 8];
#pragma unroll
    for (int mt = 0; mt < MT; ++mt)
#pragma unroll
      for (int nt = 0; nt < NT; ++nt)
        acc[mt][nt] = __builtin_amdgcn_mfma_f32_16x16x32_bf16(af[mt], bfv[nt], acc[mt][nt], 0, 0, 0);
    __syncthreads();
    bufo = nbufo;
  }
  // tail k-step (no stage)
  {
    short8 af[MT], bfv[NT];
#pragma unroll
    for (int mt = 0; mt < MT; ++mt) af[mt] = *(const short8*)&lds[bufo + (ar16 + mt) * 512 + lane * 8];
#pragma unroll
    for (int nt = 0; nt < NT; ++nt) bfv[nt] = *(const short8*)&lds[bufo + (bc16 + nt) * 512 + lane * 8];
#pragma unroll
    for (int mt = 0; mt < MT; ++mt)
#pragma unroll
      for (int nt = 0; nt < NT; ++nt)
        acc[mt][nt] = __builtin_amdgcn_mfma_f32_16x16x32_bf16(af[mt], bfv[nt], acc[mt][nt], 0, 0, 0);
  }

  if (BM == 128 && mode == 2) {
    // gelu(acc+bias) -> per-wave LDS shuffle -> packed bf16 (Kd = N)
    __syncthreads();  // staging buffers reused as shuffle space
    ushort_t* Cb = &lds[w * 5120];
#pragma unroll
    for (int mt = 0; mt < MT; ++mt)
#pragma unroll
      for (int nt = 0; nt < NT; ++nt) {
        floatx4 a4 = acc[mt][nt];
#pragma unroll
        for (int r = 0; r < 4; ++r) {
          float val = a4[r] + bias[wcol0 + nt * 16 + l16];
          val = 0.5f * val * (1.f + erff(val * 0.7071067811865475f));
          Cb[(mt * 16 + quad * 4 + r) * 80 + nt * 16 + l16] = f2bf(val);
        }
      }
#pragma unroll
    for (int mt2 = 0; mt2 < 4; ++mt2)
#pragma unroll
      for (int kt2 = 0; kt2 < 2; ++kt2) {
        short8 v8 = *(const short8*)&Cb[(mt2 * 16 + l16) * 80 + kt2 * 32 + quad * 8];
        size_t ad = ((((size_t)(wrow0 >> 4) + mt2) * (N >> 5) + (wcol0 >> 5) + kt2) << 9) + lane * 8;
        *(short8*)(outB + ad) = v8;
      }
  } else {
    const float qscale = (mode == 3 && col0 < 512) ? 0.125f : 1.0f;  // pre-scale Q for attn
#pragma unroll
    for (int mt = 0; mt < MT; ++mt)
#pragma unroll
      for (int nt = 0; nt < NT; ++nt) {
        floatx4 a4 = acc[mt][nt];
#pragma unroll
        for (int r = 0; r < 4; ++r) {
          int row = wrow0 + mt * 16 + quad * 4 + r;
          int col = wcol0 + nt * 16 + l16;
          float val = a4[r];
          if (bias) val += bias[col];
          size_t idx = (size_t)row * N + col;
          if (mode == 1) outF[idx] = val + resid[idx];
          else outB[idx] = f2bf(val * qscale);
        }
      }
  }
}

// ---------------- MFMA flash attention, fixed-max softmax ----------------
__global__ __launch_bounds__(256) void k_attn(const ushort_t* __restrict__ qkv,
                                              const int* __restrict__ lengths,
                                              ushort_t* __restrict__ o) {
  __shared__ ushort_t Ks[64 * 72];
  __shared__ ushort_t Vt[64 * 72];
  __shared__ ushort_t Ps[4][16 * 72];  // stride 72: 2-way banks only (m136-free)
  const int tid = threadIdx.x;
  const int w = tid >> 6, lane = tid & 63;
  const int quad = lane >> 4, l16 = lane & 15;
  const int tile = blockIdx.x & 15;
  const int bh = blockIdx.x >> 4;
  const int b = bh >> 3, h = bh & 7;
  const int len = lengths[b];
  if (tile * 64 >= len) return;  // block-uniform: all waves exit together
  const int tqa = tile * 64 + w * 16 + l16;
  const ushort_t* qp = qkv + ((size_t)(b * TT + tqa)) * 1536 + h * HSZ + quad * 8;
  short8 qf0 = *(const short8*)qp;
  short8 qf1 = *(const short8*)(qp + 32);
  floatx4 oacc[4] = {};
  float lsum[4] = {0.f, 0.f, 0.f, 0.f};
  const int skey = tid >> 2, sseg = (tid & 3) << 4;
  const int vkp = (tid & 31) << 1, vds = (tid >> 5) << 3;
  const int nkt = (len + 63) >> 6;
  for (int kt = 0; kt < nkt; ++kt) {
    const int s0 = kt * 64;
    __syncthreads();
    {
      const ushort_t* kp = qkv + ((size_t)(b * TT + s0 + skey)) * 1536 + 512 + h * HSZ + sseg;
      short8 k0 = *(const short8*)kp;
      short8 k1 = *(const short8*)(kp + 8);
      *(short8*)&Ks[skey * 72 + sseg] = k0;
      *(short8*)&Ks[skey * 72 + sseg + 8] = k1;
      const ushort_t* vp0 = qkv + ((size_t)(b * TT + s0 + vkp)) * 1536 + 1024 + h * HSZ + vds;
      short8 v0 = *(const short8*)vp0;
      short8 v1 = *(const short8*)(vp0 + 1536);
#pragma unroll
      for (int i = 0; i < 8; ++i) {
        ushort2 pr;
        pr.x = (ushort_t)v0[i];
        pr.y = (ushort_t)v1[i];
        *(ushort2*)&Vt[(vds + i) * 72 + vkp] = pr;
      }
    }
    __syncthreads();
    floatx4 sacc[4] = {};
#pragma unroll
    for (int nt = 0; nt < 4; ++nt) {
      short8 kf0 = *(const short8*)&Ks[(nt * 16 + l16) * 72 + quad * 8];
      short8 kf1 = *(const short8*)&Ks[(nt * 16 + l16) * 72 + 32 + quad * 8];
      sacc[nt] = __builtin_amdgcn_mfma_f32_16x16x32_bf16(qf0, kf0, sacc[nt], 0, 0, 0);
      sacc[nt] = __builtin_amdgcn_mfma_f32_16x16x32_bf16(qf1, kf1, sacc[nt], 0, 0, 0);
    }
    // p = exp(score); mask only the tail tile (wave-uniform branch)
    float p[4][4];
    if (kt == nkt - 1) {
#pragma unroll
      for (int nt = 0; nt < 4; ++nt) {
        bool valid = (s0 + nt * 16 + l16 < len);
#pragma unroll
        for (int r = 0; r < 4; ++r) p[nt][r] = valid ? __expf(sacc[nt][r]) : 0.f;
      }
    } else {
#pragma unroll
      for (int nt = 0; nt < 4; ++nt)
#pragma unroll
        for (int r = 0; r < 4; ++r) p[nt][r] = __expf(sacc[nt][r]);
    }
#pragma unroll
    for (int r = 0; r < 4; ++r)
#pragma unroll
      for (int nt = 0; nt < 4; ++nt) {
        lsum[r] += p[nt][r];
        Ps[w][(quad * 4 + r) * 72 + nt * 16 + l16] = f2bf(p[nt][r]);
      }
    short8 pf0 = *(const short8*)&Ps[w][l16 * 72 + quad * 8];
    short8 pf1 = *(const short8*)&Ps[w][l16 * 72 + 32 + quad * 8];
#pragma unroll
    for (int nt = 0; nt < 4; ++nt) {
      short8 vf0 = *(const short8*)&Vt[(nt * 16 + l16) * 72 + quad * 8];
      short8 vf1 = *(const short8*)&Vt[(nt * 16 + l16) * 72 + 32 + quad * 8];
      oacc[nt] = __builtin_amdgcn_mfma_f32_16x16x32_bf16(pf0, vf0, oacc[nt], 0, 0, 0);
      oacc[nt] = __builtin_amdgcn_mfma_f32_16x16x32_bf16(pf1, vf1, oacc[nt], 0, 0, 0);
    }
  }
  // one deferred row-sum reduction across the 16 key-lanes
#pragma unroll
  for (int off = 1; off < 16; off <<= 1) {
#pragma unroll
    for (int r = 0; r < 4; ++r) lsum[r] += __shfl_xor(lsum[r], off, 64);
  }
  // epilogue: per-wave LDS shuffle into packed-A layout (Kd=512)
#pragma unroll
  for (int r = 0; r < 4; ++r) {
    int t = tile * 64 + w * 16 + quad * 4 + r;
    float inv = (t < len) ? 1.f / lsum[r] : 0.f;  // row mask
#pragma unroll
    for (int nt = 0; nt < 4; ++nt)
      Ps[w][(quad * 4 + r) * 72 + nt * 16 + l16] = f2bf(oacc[nt][r] * inv);
  }
  const int mtile = b * 64 + tile * 4 + w;
#pragma unroll
  for (int kt2 = 0; kt2 < 2; ++kt2) {
    short8 v8 = *(const short8*)&Ps[w][l16 * 72 + kt2 * 32 + quad * 8];
    size_t ad = (((size_t)mtile * 16 + h * 2 + kt2) << 9) + lane * 8;
    *(short8*)(o + ad) = v8;
  }
}

// ---------------- pool softmax: scores -> weights (per batch) ----------------
__global__ __launch_bounds__(256) void k_softw(const float* __restrict__ scores,
                                               const int* __restrict__ lengths,
                                               float* __restrict__ wts) {
  __shared__ float red[8];
  int tid = threadIdx.x, b = blockIdx.x;
  int len = lengths[b];
  const float* sb = scores + b * TT;
  float m = -1e30f;
  for (int t = tid; t < len; t += 256) m = fmaxf(m, sb[t]);
#pragma unroll
  for (int off = 32; off; off >>= 1) m = fmaxf(m, __shfl_down(m, off, 64));
  if ((tid & 63) == 0) red[tid >> 6] = m;
  __syncthreads();
  m = fmaxf(fmaxf(red[0], red[1]), fmaxf(red[2], red[3]));
  float ssum = 0.f;
  for (int t = tid; t < len; t += 256) ssum += __expf(sb[t] - m);
#pragma unroll
  for (int off = 32; off; off >>= 1) ssum += __shfl_down(ssum, off, 64);
  if ((tid & 63) == 0) red[4 + (tid >> 6)] = ssum;
  __syncthreads();
  float inv = 1.f / (red[4] + red[5] + red[6] + red[7]);
  for (int t = tid; t < TT; t += 256)
    wts[b * TT + t] = (t < len) ? __expf(sb[t] - m) * inv : 0.f;
}

// ---------------- weighted sum partials: grid (B, 16), 64 rows each ----------------
__global__ __launch_bounds__(256) void k_wsum(const float* __restrict__ xf,
                                              const float* __restrict__ wts,
                                              float* __restrict__ partial,
                                              const int* __restrict__ lengths) {
  int b = blockIdx.x, c = blockIdx.y, tid = threadIdx.x;
  float* pp = partial + ((size_t)b * 16 + c) * DD;
  if (c * 64 >= lengths[b]) {  // dead chunk: weights all zero
    pp[tid] = 0.f;
    pp[tid + 256] = 0.f;
    return;
  }
  const float* xb = xf + ((size_t)b * TT + c * 64) * DD;
  const float* wb = wts + b * TT + c * 64;
  float a0 = 0.f, a1 = 0.f;
  for (int t = 0; t < 64; ++t) {
    float wv = wb[t];
    a0 += wv * xb[(size_t)t * DD + tid];
    a1 += wv * xb[(size_t)t * DD + tid + 256];
  }
  pp[tid] = a0;
  pp[tid + 256] = a1;
}

// ---------------- classification head (reduces the 16 partials) ----------------
__global__ __launch_bounds__(64) void k_head(const float* __restrict__ partial,
                                             const float* __restrict__ head_w,
                                             const float* __restrict__ head_b,
                                             float* __restrict__ out) {
  __shared__ float ssum[DD];
  int b = blockIdx.x, tid = threadIdx.x;
  for (int d = tid; d < DD; d += 64) {
    float s = 0.f;
#pragma unroll
    for (int c = 0; c < 16; ++c) s += partial[((size_t)b * 16 + c) * DD + d];
    ssum[d] = s;
  }
  __syncthreads();
  if (tid < 49) {
    float s = head_b[tid];
    for (int d = 0; d < DD; ++d) s += ssum[d] * head_w[d * 49 + tid];
    out[b * 49 + tid] = s;
  }
}

extern "C" void kernel_launch(void* const* d_in, const int* in_sizes, int n_in,
                              void* d_out, int out_size, void* d_ws, size_t ws_size,
                              hipStream_t stream) {
  const int* code = (const int*)d_in[0];
  const int* lengths = (const int*)d_in[1];
  const float* emb = (const float*)d_in[2];
  const float* Wq = (const float*)d_in[3];
  const float* Wk = (const float*)d_in[4];
  const float* Wv = (const float*)d_in[5];
  const float* Wo = (const float*)d_in[6];
  const float* bo = (const float*)d_in[7];
  const float* W1 = (const float*)d_in[8];
  const float* b1 = (const float*)d_in[9];
  const float* W2 = (const float*)d_in[10];
  const float* b2 = (const float*)d_in[11];
  const float* ln1_g = (const float*)d_in[12];
  const float* ln1_b = (const float*)d_in[13];
  const float* ln2_g = (const float*)d_in[14];
  const float* ln2_b = (const float*)d_in[15];
  const float* lnf_g = (const float*)d_in[16];
  const float* lnf_b = (const float*)d_in[17];
  const float* attn_w = (const float*)d_in[18];
  const float* attn_b = (const float*)d_in[19];
  const float* head_w = (const float*)d_in[20];
  const float* head_b = (const float*)d_in[21];
  float* out = (float*)d_out;

  const size_t NTOK = (size_t)BB * TT;  // 8192
  float* x = (float*)d_ws;                       // 8192*512 fp32
  ushort_t* xn = (ushort_t*)(x + NTOK * DD);     // 8192*512 bf16 (packed)
  ushort_t* un = xn + NTOK * DD;                 // union: qkv | h1 | xf
  ushort_t* qkv = un;                            // linear bf16
  ushort_t* h1 = un;                             // packed bf16
  float* xf = (float*)un;
  ushort_t* wqpk = un + (size_t)NTOK * FF4;      // packed 6x 1536x512
  ushort_t* wopk = wqpk + (size_t)LL * 1536 * 512;
  ushort_t* w1pk = wopk + (size_t)LL * 512 * 512;
  ushort_t* w2pk = w1pk + (size_t)LL * 512 * FF4;
  float* scores = (float*)(w2pk + (size_t)LL * FF4 * 512);  // 8192
  float* wts = scores + NTOK;                               // 8192
  float* partial = wts + NTOK;                              // 8*16*512

  // weight packing (fp32 [k][n] -> packed bf16 fragments)
  k_packw<<<dim3(8, 1, 48), 256, 0, stream>>>(Wq, wqpk,              64, (long)512 * 64, 8, (long)1536 * 512, 64, 512);
  k_packw<<<dim3(8, 1, 48), 256, 0, stream>>>(Wk, wqpk + 512 * 512,  64, (long)512 * 64, 8, (long)1536 * 512, 64, 512);
  k_packw<<<dim3(8, 1, 48), 256, 0, stream>>>(Wv, wqpk + 1024 * 512, 64, (long)512 * 64, 8, (long)1536 * 512, 64, 512);
  k_packw<<<dim3(8, 8, 6), 256, 0, stream>>>(Wo, wopk, 512, (long)512 * 512, 1, (long)512 * 512, 0, 512);
  k_packw<<<dim3(8, 32, 6), 256, 0, stream>>>(W1, w1pk, 2048, (long)512 * 2048, 1, (long)2048 * 512, 0, 512);
  k_packw<<<dim3(32, 8, 6), 256, 0, stream>>>(W2, w2pk, 512, (long)2048 * 512, 1, (long)512 * 2048, 0, 2048);

  k_embed<<<dim3((unsigned)((NTOK * DD) / 256)), dim3(256), 0, stream>>>(code, emb, x, lengths);

  for (int l = 0; l < LL; ++l) {
    k_ln<<<dim3(NTOK / 4), 256, 0, stream>>>(x, xn, nullptr, ln1_g + l * DD, ln1_b + l * DD,
                                             nullptr, nullptr, nullptr, lengths);
    // QKV (mode 3): 128x128 tiles -> 768 blocks
    k_agemm<128, 128><<<dim3(768), 256, 0, stream>>>(xn, wqpk + (size_t)l * 1536 * 512, nullptr, nullptr,
                                                     nullptr, qkv, (int)NTOK, 1536, 512, 3, lengths);
    k_attn<<<dim3(BB * HH * (TT / 64)), 256, 0, stream>>>(qkv, lengths, xn);
    // Wo + bias + residual -> x (fp32): 64x64 tiles -> 1024 blocks
    k_agemm<64, 64><<<dim3(1024), 256, 0, stream>>>(xn, wopk + (size_t)l * 512 * 512, x, bo + l * DD,
                                                    x, nullptr, (int)NTOK, 512, 512, 1, lengths);
    k_ln<<<dim3(NTOK / 4), 256, 0, stream>>>(x, xn, nullptr, ln2_g + l * DD, ln2_b + l * DD,
                                             nullptr, nullptr, nullptr, lengths);
    // W1 + bias + GELU -> h1 (packed bf16): 128x128 tiles -> 1024 blocks
    k_agemm<128, 128><<<dim3(1024), 256, 0, stream>>>(xn, w1pk + (size_t)l * 512 * FF4, nullptr, b1 + l * FF4,
                                                      nullptr, h1, (int)NTOK, FF4, 512, 2, lengths);
    // W2 + bias + residual -> x (fp32): K=2048, 64x64 tiles -> 1024 blocks
    k_agemm<64, 64><<<dim3(1024), 256, 0, stream>>>(h1, w2pk + (size_t)l * FF4 * 512, x, b2 + l * DD,
                                                    x, nullptr, (int)NTOK, 512, 2048, 1, lengths);
  }
  k_ln<<<dim3(NTOK / 4), 256, 0, stream>>>(x, nullptr, xf, lnf_g, lnf_b,
                                           attn_w, attn_b, scores, lengths);
  k_softw<<<dim3(BB), 256, 0, stream>>>(scores, lengths, wts);
  k_wsum<<<dim3(BB, 16), 256, 0, stream>>>(xf, wts, partial, lengths);
  k_head<<<dim3(BB), 64, 0, stream>>>(partial, head_w, head_b, out);
}

// Round 5
// 1210.753 us; speedup vs baseline: 1.1513x; 1.0210x over previous
//
#include <hip/hip_runtime.h>
#include <math.h>

#define TT 1024
#define BB 8
#define DD 512
#define HH 8
#define HSZ 64
#define LL 6
#define FF4 2048

typedef __attribute__((ext_vector_type(8))) short short8;
typedef __attribute__((ext_vector_type(4))) float floatx4;
typedef unsigned short ushort_t;
typedef unsigned int uint_t;

__device__ __forceinline__ ushort_t f2bf(float f) {
  uint_t u = __float_as_uint(f);
  u += 0x7fff + ((u >> 16) & 1);  // RNE
  return (ushort_t)(u >> 16);
}
__device__ __forceinline__ float bf2f(ushort_t h) {
  return __uint_as_float(((uint_t)h) << 16);
}

// async global->LDS DMA, 16B/lane. LDS dest is wave-uniform base + lane*16;
// global src is per-lane. Our packed-fragment layout is exactly this pattern.
typedef const __attribute__((address_space(1))) uint_t* gas_t;
typedef __attribute__((address_space(3))) uint_t* las_t;
__device__ __forceinline__ void stage16(const ushort_t* g, ushort_t* l) {
  __builtin_amdgcn_global_load_lds((gas_t)g, (las_t)l, 16, 0, 0);
}

#define VMWAIT(n) asm volatile("s_waitcnt vmcnt(" #n ")" ::: "memory")
#define MEMFENCE() asm volatile("" ::: "memory")

// Packed MFMA-fragment layout for a [rows x Kd] bf16 matrix:
// tile (r16=row>>4, c32=col>>5); element index =
//   ((r16*(Kd>>5)+c32)<<9) + (((col>>3)&3)*16 + (row&15))*8 + (col&7)
// A wave's fragment (16 rows x 32 cols) is one contiguous 1KB chunk,
// lane i holding bytes [i*16, i*16+16) -> one coalesced global_load_lds_dwordx4
// and one conflict-benign ds_read_b128.

// ---------------- embed + positional encoding ----------------
__global__ __launch_bounds__(256) void k_embed(const int* __restrict__ code,
                                               const float* __restrict__ emb,
                                               float* __restrict__ x,
                                               const int* __restrict__ lengths) {
  int idx = blockIdx.x * 256 + threadIdx.x;  // over B*T*D
  int c = idx & (DD - 1);
  int bt = idx >> 9;
  int t = bt & (TT - 1);
  if (t >= lengths[bt >> 10]) return;  // block-uniform (block spans half a row)
  int f = c >> 4, e = c & 15;
  int vv = code[bt * 32 + f];
  int i = c >> 1;
  float freq = expf((float)(2 * i) * (-9.210340371976184f / 512.f));
  float ang = (float)t * freq;
  float pe = (c & 1) ? cosf(ang) : sinf(ang);
  x[idx] = emb[vv * 16 + e] + pe;
}

// ---------------- layernorm: fp32 in -> packed bf16 (or linear fp32 + scores) ----------------
__global__ __launch_bounds__(256) void k_ln(const float* __restrict__ x,
                                            ushort_t* __restrict__ yB,
                                            float* __restrict__ yF,
                                            const float* __restrict__ g,
                                            const float* __restrict__ b,
                                            const float* __restrict__ aw,
                                            const float* __restrict__ ab,
                                            float* __restrict__ scores,
                                            const int* __restrict__ lengths) {
  int row0 = blockIdx.x * 4;
  if ((row0 & (TT - 1)) >= lengths[row0 >> 10]) return;  // 4 rows share a batch
  int wave = threadIdx.x >> 6, lane = threadIdx.x & 63;
  int row = row0 + wave;
  const float* xr = x + (size_t)row * DD;
  float v[8];
  *(float4*)&v[0] = *(const float4*)(xr + lane * 8);
  *(float4*)&v[4] = *(const float4*)(xr + lane * 8 + 4);
  float s = 0.f;
#pragma unroll
  for (int j = 0; j < 8; ++j) s += v[j];
#pragma unroll
  for (int off = 32; off; off >>= 1) s += __shfl_down(s, off, 64);
  float mean = __shfl(s, 0, 64) * (1.f / DD);
  float qv = 0.f;
#pragma unroll
  for (int j = 0; j < 8; ++j) { float d = v[j] - mean; qv += d * d; }
#pragma unroll
  for (int off = 32; off; off >>= 1) qv += __shfl_down(qv, off, 64);
  float rs = rsqrtf(__shfl(qv, 0, 64) * (1.f / DD) + 1e-5f);
  float ov[8];
  float sdot = 0.f;
#pragma unroll
  for (int e = 0; e < 8; ++e) {
    int c = lane * 8 + e;
    ov[e] = (v[e] - mean) * rs * g[c] + b[c];
    if (scores) sdot += ov[e] * aw[c];
  }
  if (yB) {
    short8 o8;
#pragma unroll
    for (int e = 0; e < 8; ++e) o8[e] = (short)f2bf(ov[e]);
    size_t ad = (((size_t)(row >> 4) * 16 + (lane >> 2)) << 9) + ((lane & 3) * 16 + (row & 15)) * 8;
    *(short8*)(yB + ad) = o8;
  } else {
    float* yr = yF + (size_t)row * DD + lane * 8;
    *(float4*)yr = *(float4*)&ov[0];
    *(float4*)(yr + 4) = *(float4*)&ov[4];
  }
  if (scores) {
#pragma unroll
    for (int off = 32; off; off >>= 1) sdot += __shfl_down(sdot, off, 64);
    if (lane == 0) scores[row] = sdot + ab[0];
  }
}

// ---------------- fp32 weights -> packed bf16 B-operand ----------------
__global__ __launch_bounds__(256) void k_packw(const float* __restrict__ in,
                                               ushort_t* __restrict__ out,
                                               int Nin, long in_ms, int nh,
                                               long os_l, int nblk, int Kout) {
  __shared__ float t4[64][65];
  int mz = blockIdx.z;
  const float* ip = in + (size_t)mz * in_ms;
  ushort_t* op = out + (size_t)(mz / nh) * os_l;
  int nbase = (mz % nh) * nblk + blockIdx.y * 64;
  int k0 = blockIdx.x * 64;
  int cc = threadIdx.x & 63, r0 = threadIdx.x >> 6;
#pragma unroll
  for (int i = 0; i < 16; ++i) {
    int r = r0 * 16 + i;
    t4[r][cc] = ip[(size_t)(k0 + r) * Nin + (nbase - (mz % nh) * nblk) + cc];
  }
  __syncthreads();
#pragma unroll
  for (int half = 0; half < 2; ++half) {
    int c = threadIdx.x + half * 256;
    int joct = c >> 6, nl = c & 63;
    int n = nbase + nl, k = k0 + joct * 8;
    short8 v8;
#pragma unroll
    for (int e = 0; e < 8; ++e) v8[e] = (short)f2bf(t4[joct * 8 + e][nl]);
    size_t ad = (((size_t)(n >> 4) * (Kout >> 5) + (k >> 5)) << 9) + (((k >> 3) & 3) * 16 + (n & 15)) * 8;
    *(short8*)(op + ad) = v8;
  }
}

// ---------------- staged MFMA GEMM: 4 waves, global_load_lds + counted vmcnt ----------------
// R4 post-mortem: __syncthreads() drains vmcnt(0) each k-step, so the just-issued
// next-tile DMAs serialize (full ~300cy latency per step). T4 fix: raw s_barrier
// + counted s_waitcnt vmcnt(N) so prefetch DMAs stay in flight across barriers.
// 128x128 (QKV/W1): 2 buffers (NF=4/wave), main wait vmcnt(4), tail vmcnt(0).
// 64x64 (Wo/W2): 4 buffers depth-3 (NF=2/wave), main vmcnt(6), drain 4->2->0
//   (compute phase is only 4 MFMA, needs the deep pipeline).
// Sync proof: slot s is overwritten only NBUF-1 iters after its post-read
// barrier; pre-compute {own-vmcnt wait; s_barrier} makes all waves' fragments
// of tile kc visible before any ds_read.
// mode 0: outB linear bf16; mode 3: same + q-part (col<512) scaled by 0.125;
// mode 1: outF = acc+bias+resid (fp32); mode 2 (BM=128): outB packed bf16 gelu.
// lengths: M-tiles fully past len[batch] are dead -> skip block.
template <int BM, int BN>
__global__ __launch_bounds__(256, (BM == 128) ? 3 : 4) void k_agemm(const ushort_t* __restrict__ Apk,
                                                                    const ushort_t* __restrict__ Bpk,
                                                                    const float* __restrict__ resid,
                                                                    const float* __restrict__ bias,
                                                                    float* __restrict__ outF,
                                                                    ushort_t* __restrict__ outB,
                                                                    int M, int N, int K, int mode,
                                                                    const int* __restrict__ lengths) {
  constexpr int MT = BM / 32;      // MFMA row-frags per wave
  constexpr int NT = BN / 32;      // MFMA col-frags per wave
  constexpr int NA = BM / 16;      // A fragments per k-step
  constexpr int NB = BN / 16;      // B fragments per k-step
  constexpr int NFRAG = NA + NB;
  constexpr int NF = NFRAG / 4;    // fragments staged per wave per k-step
  constexpr int BUFU = NFRAG * 512;  // ushort units per buffer (1KB/frag)
  constexpr int NBUF = (BM == 128) ? 2 : 4;
  // BM=128: mode-2 epilogue shuffle needs 4 waves x 10KB = 40KB (> 2x16KB dbuf).
  __shared__ ushort_t lds[(BM == 128) ? 20480 : NBUF * BUFU];

  const int tid = threadIdx.x;
  const int w = tid >> 6, lane = tid & 63;
  const int quad = lane >> 4, l16 = lane & 15;
  const int gx = N / BN;
  int id = blockIdx.x;
  int bx = (id >> 3) % gx;
  int by = (id / (8 * gx)) * 8 + (id & 7);  // same-row tiles share an XCD
  const int row0 = by * BM, col0 = bx * BN;
  if (lengths && (row0 & (TT - 1)) >= lengths[row0 >> 10]) return;
  const int nk = K >> 5;

  // wave's quadrant within the block tile
  const int wrow0 = row0 + (w >> 1) * (BM / 2);
  const int wcol0 = col0 + (w & 1) * (BN / 2);
  const int ar16 = (w >> 1) * MT;        // first A slot for this wave
  const int bc16 = NA + (w & 1) * NT;    // first B slot for this wave

  // per-wave stage sources (fragment base + lane*16B) and LDS slot offsets
  const ushort_t* gsrc[NF];
  int slot[NF];
#pragma unroll
  for (int i = 0; i < NF; ++i) {
    int f = w * NF + i;
    if (f < NA)
      gsrc[i] = Apk + (((size_t)((row0 >> 4) + f) * nk) << 9) + lane * 8;
    else
      gsrc[i] = Bpk + (((size_t)((col0 >> 4) + (f - NA)) * nk) << 9) + lane * 8;
    slot[i] = f * 512;
  }

  floatx4 acc[MT][NT] = {};

  auto computeStep = [&](int bb) {
    const int base = bb * BUFU;
    short8 af[MT], bfv[NT];
#pragma unroll
    for (int mt = 0; mt < MT; ++mt) af[mt] = *(const short8*)&lds[base + (ar16 + mt) * 512 + lane * 8];
#pragma unroll
    for (int nt = 0; nt < NT; ++nt) bfv[nt] = *(const short8*)&lds[base + (bc16 + nt) * 512 + lane * 8];
#pragma unroll
    for (int mt = 0; mt < MT; ++mt)
#pragma unroll
      for (int nt = 0; nt < NT; ++nt)
        acc[mt][nt] = __builtin_amdgcn_mfma_f32_16x16x32_bf16(af[mt], bfv[nt], acc[mt][nt], 0, 0, 0);
  };

  // prologue: stage tiles 0..NBUF-2
#pragma unroll
  for (int p = 0; p < NBUF - 1; ++p)
#pragma unroll
    for (int i = 0; i < NF; ++i)
      stage16(gsrc[i] + ((size_t)p << 9), &lds[p * BUFU + slot[i]]);

  // main loop: stage tile kc+NBUF-1, wait own tile-kc DMAs, barrier, compute
  int kc = 0;
  for (; kc + NBUF - 1 < nk; ++kc) {
    const int sslot = (kc + NBUF - 1) & (NBUF - 1);
#pragma unroll
    for (int i = 0; i < NF; ++i)
      stage16(gsrc[i] + ((size_t)(kc + NBUF - 1) << 9), &lds[sslot * BUFU + slot[i]]);
    if constexpr (BM == 128) VMWAIT(4);   // (NBUF-1)*NF = 1*4
    else VMWAIT(6);                       // 3*2
    __builtin_amdgcn_s_barrier();
    MEMFENCE();
    computeStep(kc & (NBUF - 1));
    MEMFENCE();
    __builtin_amdgcn_s_barrier();
  }
  // drain epilogue: remaining NBUF-1 tiles, decreasing waits
  if constexpr (NBUF == 2) {
    VMWAIT(0);
    __builtin_amdgcn_s_barrier();
    MEMFENCE();
    computeStep(kc & 1);
  } else {
    VMWAIT(4);
    __builtin_amdgcn_s_barrier();
    MEMFENCE();
    computeStep(kc & 3);
    VMWAIT(2);
    __builtin_amdgcn_s_barrier();
    MEMFENCE();
    computeStep((kc + 1) & 3);
    VMWAIT(0);
    __builtin_amdgcn_s_barrier();
    MEMFENCE();
    computeStep((kc + 2) & 3);
  }

  if (BM == 128 && mode == 2) {
    // gelu(acc+bias) -> per-wave LDS shuffle -> packed bf16 (Kd = N)
    __syncthreads();  // staging buffers reused as shuffle space
    ushort_t* Cb = &lds[w * 5120];
#pragma unroll
    for (int mt = 0; mt < MT; ++mt)
#pragma unroll
      for (int nt = 0; nt < NT; ++nt) {
        floatx4 a4 = acc[mt][nt];
#pragma unroll
        for (int r = 0; r < 4; ++r) {
          float val = a4[r] + bias[wcol0 + nt * 16 + l16];
          val = 0.5f * val * (1.f + erff(val * 0.7071067811865475f));
          Cb[(mt * 16 + quad * 4 + r) * 80 + nt * 16 + l16] = f2bf(val);
        }
      }
#pragma unroll
    for (int mt2 = 0; mt2 < 4; ++mt2)
#pragma unroll
      for (int kt2 = 0; kt2 < 2; ++kt2) {
        short8 v8 = *(const short8*)&Cb[(mt2 * 16 + l16) * 80 + kt2 * 32 + quad * 8];
        size_t ad = ((((size_t)(wrow0 >> 4) + mt2) * (N >> 5) + (wcol0 >> 5) + kt2) << 9) + lane * 8;
        *(short8*)(outB + ad) = v8;
      }
  } else {
    const float qscale = (mode == 3 && col0 < 512) ? 0.125f : 1.0f;  // pre-scale Q for attn
#pragma unroll
    for (int mt = 0; mt < MT; ++mt)
#pragma unroll
      for (int nt = 0; nt < NT; ++nt) {
        floatx4 a4 = acc[mt][nt];
#pragma unroll
        for (int r = 0; r < 4; ++r) {
          int row = wrow0 + mt * 16 + quad * 4 + r;
          int col = wcol0 + nt * 16 + l16;
          float val = a4[r];
          if (bias) val += bias[col];
          size_t idx = (size_t)row * N + col;
          if (mode == 1) outF[idx] = val + resid[idx];
          else outB[idx] = f2bf(val * qscale);
        }
      }
  }
}

// ---------------- MFMA flash attention, fixed-max softmax ----------------
__global__ __launch_bounds__(256) void k_attn(const ushort_t* __restrict__ qkv,
                                              const int* __restrict__ lengths,
                                              ushort_t* __restrict__ o) {
  __shared__ ushort_t Ks[64 * 72];
  __shared__ ushort_t Vt[64 * 72];
  __shared__ ushort_t Ps[4][16 * 72];  // stride 72: 2-way banks only (m136-free)
  const int tid = threadIdx.x;
  const int w = tid >> 6, lane = tid & 63;
  const int quad = lane >> 4, l16 = lane & 15;
  const int tile = blockIdx.x & 15;
  const int bh = blockIdx.x >> 4;
  const int b = bh >> 3, h = bh & 7;
  const int len = lengths[b];
  if (tile * 64 >= len) return;  // block-uniform: all waves exit together
  const int tqa = tile * 64 + w * 16 + l16;
  const ushort_t* qp = qkv + ((size_t)(b * TT + tqa)) * 1536 + h * HSZ + quad * 8;
  short8 qf0 = *(const short8*)qp;
  short8 qf1 = *(const short8*)(qp + 32);
  floatx4 oacc[4] = {};
  float lsum[4] = {0.f, 0.f, 0.f, 0.f};
  const int skey = tid >> 2, sseg = (tid & 3) << 4;
  const int vkp = (tid & 31) << 1, vds = (tid >> 5) << 3;
  const int nkt = (len + 63) >> 6;
  for (int kt = 0; kt < nkt; ++kt) {
    const int s0 = kt * 64;
    __syncthreads();
    {
      const ushort_t* kp = qkv + ((size_t)(b * TT + s0 + skey)) * 1536 + 512 + h * HSZ + sseg;
      short8 k0 = *(const short8*)kp;
      short8 k1 = *(const short8*)(kp + 8);
      *(short8*)&Ks[skey * 72 + sseg] = k0;
      *(short8*)&Ks[skey * 72 + sseg + 8] = k1;
      const ushort_t* vp0 = qkv + ((size_t)(b * TT + s0 + vkp)) * 1536 + 1024 + h * HSZ + vds;
      short8 v0 = *(const short8*)vp0;
      short8 v1 = *(const short8*)(vp0 + 1536);
#pragma unroll
      for (int i = 0; i < 8; ++i) {
        ushort2 pr;
        pr.x = (ushort_t)v0[i];
        pr.y = (ushort_t)v1[i];
        *(ushort2*)&Vt[(vds + i) * 72 + vkp] = pr;
      }
    }
    __syncthreads();
    floatx4 sacc[4] = {};
#pragma unroll
    for (int nt = 0; nt < 4; ++nt) {
      short8 kf0 = *(const short8*)&Ks[(nt * 16 + l16) * 72 + quad * 8];
      short8 kf1 = *(const short8*)&Ks[(nt * 16 + l16) * 72 + 32 + quad * 8];
      sacc[nt] = __builtin_amdgcn_mfma_f32_16x16x32_bf16(qf0, kf0, sacc[nt], 0, 0, 0);
      sacc[nt] = __builtin_amdgcn_mfma_f32_16x16x32_bf16(qf1, kf1, sacc[nt], 0, 0, 0);
    }
    // p = exp(score); mask only the tail tile (wave-uniform branch)
    float p[4][4];
    if (kt == nkt - 1) {
#pragma unroll
      for (int nt = 0; nt < 4; ++nt) {
        bool valid = (s0 + nt * 16 + l16 < len);
#pragma unroll
        for (int r = 0; r < 4; ++r) p[nt][r] = valid ? __expf(sacc[nt][r]) : 0.f;
      }
    } else {
#pragma unroll
      for (int nt = 0; nt < 4; ++nt)
#pragma unroll
        for (int r = 0; r < 4; ++r) p[nt][r] = __expf(sacc[nt][r]);
    }
#pragma unroll
    for (int r = 0; r < 4; ++r)
#pragma unroll
      for (int nt = 0; nt < 4; ++nt) {
        lsum[r] += p[nt][r];
        Ps[w][(quad * 4 + r) * 72 + nt * 16 + l16] = f2bf(p[nt][r]);
      }
    short8 pf0 = *(const short8*)&Ps[w][l16 * 72 + quad * 8];
    short8 pf1 = *(const short8*)&Ps[w][l16 * 72 + 32 + quad * 8];
#pragma unroll
    for (int nt = 0; nt < 4; ++nt) {
      short8 vf0 = *(const short8*)&Vt[(nt * 16 + l16) * 72 + quad * 8];
      short8 vf1 = *(const short8*)&Vt[(nt * 16 + l16) * 72 + 32 + quad * 8];
      oacc[nt] = __builtin_amdgcn_mfma_f32_16x16x32_bf16(pf0, vf0, oacc[nt], 0, 0, 0);
      oacc[nt] = __builtin_amdgcn_mfma_f32_16x16x32_bf16(pf1, vf1, oacc[nt], 0, 0, 0);
    }
  }
  // one deferred row-sum reduction across the 16 key-lanes
#pragma unroll
  for (int off = 1; off < 16; off <<= 1) {
#pragma unroll
    for (int r = 0; r < 4; ++r) lsum[r] += __shfl_xor(lsum[r], off, 64);
  }
  // epilogue: per-wave LDS shuffle into packed-A layout (Kd=512)
#pragma unroll
  for (int r = 0; r < 4; ++r) {
    int t = tile * 64 + w * 16 + quad * 4 + r;
    float inv = (t < len) ? 1.f / lsum[r] : 0.f;  // row mask
#pragma unroll
    for (int nt = 0; nt < 4; ++nt)
      Ps[w][(quad * 4 + r) * 72 + nt * 16 + l16] = f2bf(oacc[nt][r] * inv);
  }
  const int mtile = b * 64 + tile * 4 + w;
#pragma unroll
  for (int kt2 = 0; kt2 < 2; ++kt2) {
    short8 v8 = *(const short8*)&Ps[w][l16 * 72 + kt2 * 32 + quad * 8];
    size_t ad = (((size_t)mtile * 16 + h * 2 + kt2) << 9) + lane * 8;
    *(short8*)(o + ad) = v8;
  }
}

// ---------------- pool softmax: scores -> weights (per batch) ----------------
__global__ __launch_bounds__(256) void k_softw(const float* __restrict__ scores,
                                               const int* __restrict__ lengths,
                                               float* __restrict__ wts) {
  __shared__ float red[8];
  int tid = threadIdx.x, b = blockIdx.x;
  int len = lengths[b];
  const float* sb = scores + b * TT;
  float m = -1e30f;
  for (int t = tid; t < len; t += 256) m = fmaxf(m, sb[t]);
#pragma unroll
  for (int off = 32; off; off >>= 1) m = fmaxf(m, __shfl_down(m, off, 64));
  if ((tid & 63) == 0) red[tid >> 6] = m;
  __syncthreads();
  m = fmaxf(fmaxf(red[0], red[1]), fmaxf(red[2], red[3]));
  float ssum = 0.f;
  for (int t = tid; t < len; t += 256) ssum += __expf(sb[t] - m);
#pragma unroll
  for (int off = 32; off; off >>= 1) ssum += __shfl_down(ssum, off, 64);
  if ((tid & 63) == 0) red[4 + (tid >> 6)] = ssum;
  __syncthreads();
  float inv = 1.f / (red[4] + red[5] + red[6] + red[7]);
  for (int t = tid; t < TT; t += 256)
    wts[b * TT + t] = (t < len) ? __expf(sb[t] - m) * inv : 0.f;
}

// ---------------- weighted sum partials: grid (B, 16), 64 rows each ----------------
__global__ __launch_bounds__(256) void k_wsum(const float* __restrict__ xf,
                                              const float* __restrict__ wts,
                                              float* __restrict__ partial,
                                              const int* __restrict__ lengths) {
  int b = blockIdx.x, c = blockIdx.y, tid = threadIdx.x;
  float* pp = partial + ((size_t)b * 16 + c) * DD;
  if (c * 64 >= lengths[b]) {  // dead chunk: weights all zero
    pp[tid] = 0.f;
    pp[tid + 256] = 0.f;
    return;
  }
  const float* xb = xf + ((size_t)b * TT + c * 64) * DD;
  const float* wb = wts + b * TT + c * 64;
  float a0 = 0.f, a1 = 0.f;
  for (int t = 0; t < 64; ++t) {
    float wv = wb[t];
    a0 += wv * xb[(size_t)t * DD + tid];
    a1 += wv * xb[(size_t)t * DD + tid + 256];
  }
  pp[tid] = a0;
  pp[tid + 256] = a1;
}

// ---------------- classification head (reduces the 16 partials) ----------------
__global__ __launch_bounds__(64) void k_head(const float* __restrict__ partial,
                                             const float* __restrict__ head_w,
                                             const float* __restrict__ head_b,
                                             float* __restrict__ out) {
  __shared__ float ssum[DD];
  int b = blockIdx.x, tid = threadIdx.x;
  for (int d = tid; d < DD; d += 64) {
    float s = 0.f;
#pragma unroll
    for (int c = 0; c < 16; ++c) s += partial[((size_t)b * 16 + c) * DD + d];
    ssum[d] = s;
  }
  __syncthreads();
  if (tid < 49) {
    float s = head_b[tid];
    for (int d = 0; d < DD; ++d) s += ssum[d] * head_w[d * 49 + tid];
    out[b * 49 + tid] = s;
  }
}

extern "C" void kernel_launch(void* const* d_in, const int* in_sizes, int n_in,
                              void* d_out, int out_size, void* d_ws, size_t ws_size,
                              hipStream_t stream) {
  const int* code = (const int*)d_in[0];
  const int* lengths = (const int*)d_in[1];
  const float* emb = (const float*)d_in[2];
  const float* Wq = (const float*)d_in[3];
  const float* Wk = (const float*)d_in[4];
  const float* Wv = (const float*)d_in[5];
  const float* Wo = (const float*)d_in[6];
  const float* bo = (const float*)d_in[7];
  const float* W1 = (const float*)d_in[8];
  const float* b1 = (const float*)d_in[9];
  const float* W2 = (const float*)d_in[10];
  const float* b2 = (const float*)d_in[11];
  const float* ln1_g = (const float*)d_in[12];
  const float* ln1_b = (const float*)d_in[13];
  const float* ln2_g = (const float*)d_in[14];
  const float* ln2_b = (const float*)d_in[15];
  const float* lnf_g = (const float*)d_in[16];
  const float* lnf_b = (const float*)d_in[17];
  const float* attn_w = (const float*)d_in[18];
  const float* attn_b = (const float*)d_in[19];
  const float* head_w = (const float*)d_in[20];
  const float* head_b = (const float*)d_in[21];
  float* out = (float*)d_out;

  const size_t NTOK = (size_t)BB * TT;  // 8192
  float* x = (float*)d_ws;                       // 8192*512 fp32
  ushort_t* xn = (ushort_t*)(x + NTOK * DD);     // 8192*512 bf16 (packed)
  ushort_t* un = xn + NTOK * DD;                 // union: qkv | h1 | xf
  ushort_t* qkv = un;                            // linear bf16
  ushort_t* h1 = un;                             // packed bf16
  float* xf = (float*)un;
  ushort_t* wqpk = un + (size_t)NTOK * FF4;      // packed 6x 1536x512
  ushort_t* wopk = wqpk + (size_t)LL * 1536 * 512;
  ushort_t* w1pk = wopk + (size_t)LL * 512 * 512;
  ushort_t* w2pk = w1pk + (size_t)LL * 512 * FF4;
  float* scores = (float*)(w2pk + (size_t)LL * FF4 * 512);  // 8192
  float* wts = scores + NTOK;                               // 8192
  float* partial = wts + NTOK;                              // 8*16*512

  // weight packing (fp32 [k][n] -> packed bf16 fragments)
  k_packw<<<dim3(8, 1, 48), 256, 0, stream>>>(Wq, wqpk,              64, (long)512 * 64, 8, (long)1536 * 512, 64, 512);
  k_packw<<<dim3(8, 1, 48), 256, 0, stream>>>(Wk, wqpk + 512 * 512,  64, (long)512 * 64, 8, (long)1536 * 512, 64, 512);
  k_packw<<<dim3(8, 1, 48), 256, 0, stream>>>(Wv, wqpk + 1024 * 512, 64, (long)512 * 64, 8, (long)1536 * 512, 64, 512);
  k_packw<<<dim3(8, 8, 6), 256, 0, stream>>>(Wo, wopk, 512, (long)512 * 512, 1, (long)512 * 512, 0, 512);
  k_packw<<<dim3(8, 32, 6), 256, 0, stream>>>(W1, w1pk, 2048, (long)512 * 2048, 1, (long)2048 * 512, 0, 512);
  k_packw<<<dim3(32, 8, 6), 256, 0, stream>>>(W2, w2pk, 512, (long)2048 * 512, 1, (long)512 * 2048, 0, 2048);

  k_embed<<<dim3((unsigned)((NTOK * DD) / 256)), dim3(256), 0, stream>>>(code, emb, x, lengths);

  for (int l = 0; l < LL; ++l) {
    k_ln<<<dim3(NTOK / 4), 256, 0, stream>>>(x, xn, nullptr, ln1_g + l * DD, ln1_b + l * DD,
                                             nullptr, nullptr, nullptr, lengths);
    // QKV (mode 3): 128x128 tiles -> 768 blocks
    k_agemm<128, 128><<<dim3(768), 256, 0, stream>>>(xn, wqpk + (size_t)l * 1536 * 512, nullptr, nullptr,
                                                     nullptr, qkv, (int)NTOK, 1536, 512, 3, lengths);
    k_attn<<<dim3(BB * HH * (TT / 64)), 256, 0, stream>>>(qkv, lengths, xn);
    // Wo + bias + residual -> x (fp32): 64x64 tiles -> 1024 blocks
    k_agemm<64, 64><<<dim3(1024), 256, 0, stream>>>(xn, wopk + (size_t)l * 512 * 512, x, bo + l * DD,
                                                    x, nullptr, (int)NTOK, 512, 512, 1, lengths);
    k_ln<<<dim3(NTOK / 4), 256, 0, stream>>>(x, xn, nullptr, ln2_g + l * DD, ln2_b + l * DD,
                                             nullptr, nullptr, nullptr, lengths);
    // W1 + bias + GELU -> h1 (packed bf16): 128x128 tiles -> 1024 blocks
    k_agemm<128, 128><<<dim3(1024), 256, 0, stream>>>(xn, w1pk + (size_t)l * 512 * FF4, nullptr, b1 + l * FF4,
                                                      nullptr, h1, (int)NTOK, FF4, 512, 2, lengths);
    // W2 + bias + residual -> x (fp32): K=2048, 64x64 tiles -> 1024 blocks
    k_agemm<64, 64><<<dim3(1024), 256, 0, stream>>>(h1, w2pk + (size_t)l * FF4 * 512, x, b2 + l * DD,
                                                    x, nullptr, (int)NTOK, 512, 2048, 1, lengths);
  }
  k_ln<<<dim3(NTOK / 4), 256, 0, stream>>>(x, nullptr, xf, lnf_g, lnf_b,
                                           attn_w, attn_b, scores, lengths);
  k_softw<<<dim3(BB), 256, 0, stream>>>(scores, lengths, wts);
  k_wsum<<<dim3(BB, 16), 256, 0, stream>>>(xf, wts, partial, lengths);
  k_head<<<dim3(BB), 64, 0, stream>>>(partial, head_w, head_b, out);
}